// Round 1
// 1099.105 us; speedup vs baseline: 1.0868x; 1.0868x over previous
//
#include <hip/hip_runtime.h>
#include <hip/hip_bf16.h>
#include <stdint.h>

typedef __hip_bfloat16 bf16;

__device__ __forceinline__ float b2f(bf16 x) { return __bfloat162float(x); }
__device__ __forceinline__ float bits2f(uint32_t u) {
    union { uint32_t i; float f; } c; c.i = u; return c.f;
}

// ---------------------------------------------------------------------------
// Mode detection: 0 = bf16 external tensors, 1 = f32.
// ---------------------------------------------------------------------------
__global__ void detect_mode_kernel(const uint16_t* __restrict__ nf, int* __restrict__ flag) {
    if (threadIdx.x != 0 || blockIdx.x != 0) return;
    int sane = 0;
    for (int i = 0; i < 256; ++i) {
        uint32_t u = nf[2 * i];
        float a = fabsf(bits2f(u << 16));
        if (a == 0.f || (a > 1e-5f && a < 100.f)) ++sane;
    }
    flag[0] = (sane >= 128) ? 0 : 1;
}

struct ParamTable {
    const void* src[14];
    int off[15];
};

__global__ void convert_params_kernel(ParamTable T, const int* __restrict__ mode,
                                      float* __restrict__ out) {
    int i = blockIdx.x * blockDim.x + threadIdx.x;
    if (i >= T.off[14]) return;
    int k = 0;
    while (k < 13 && i >= T.off[k + 1]) ++k;
    int j = i - T.off[k];
    out[i] = (*mode == 0) ? b2f(((const bf16*)T.src[k])[j]) : ((const float*)T.src[k])[j];
}

// wae[d*3+h] = sum_f We[d*96 + h*32 + f] * ae[h*32 + f]
__global__ void fold_wae_kernel(const float* __restrict__ We, const float* __restrict__ ae,
                                float* __restrict__ wae) {
    int t = threadIdx.x;
    if (t >= 96) return;
    int d = t / 3, h = t - d * 3;
    float acc = 0.f;
    for (int f = 0; f < 32; ++f) acc += We[d * 96 + h * 32 + f] * ae[h * 32 + f];
    wae[t] = acc;
}

// ---------------------------------------------------------------------------
// CSR build: histogram -> scan.
// ---------------------------------------------------------------------------
__global__ void hist_kernel(const int* __restrict__ dst, int* __restrict__ cnt, int E) {
    int e = blockIdx.x * blockDim.x + threadIdx.x;
    if (e < E) atomicAdd(&cnt[dst[e]], 1);
}

__global__ void block_sum_kernel(const int* __restrict__ deg, int* __restrict__ bsums, int N) {
    __shared__ int sd[256];
    int t = threadIdx.x;
    int i = blockIdx.x * 256 + t;
    sd[t] = (i < N) ? deg[i] : 0;
    __syncthreads();
    for (int o = 128; o > 0; o >>= 1) {
        if (t < o) sd[t] += sd[t + o];
        __syncthreads();
    }
    if (t == 0) bsums[blockIdx.x] = sd[0];
}

__global__ void scan_bsums_kernel(int* __restrict__ bsums, int nb) {
    __shared__ int a[512], b[512];
    int t = threadIdx.x;
    int v = (t < nb) ? bsums[t] : 0;
    a[t] = v;
    __syncthreads();
    int* in = a;
    int* out = b;
    for (int o = 1; o < 512; o <<= 1) {
        out[t] = in[t] + ((t >= o) ? in[t - o] : 0);
        __syncthreads();
        int* tmp = in; in = out; out = tmp;
    }
    if (t < nb) bsums[t] = in[t] - v;
}

__global__ void scan_expand_kernel(const int* __restrict__ deg, const int* __restrict__ boffs,
                                   int* __restrict__ row_start, int N) {
    __shared__ int a[256], b[256];
    int t = threadIdx.x;
    int i = blockIdx.x * 256 + t;
    int v = (i < N) ? deg[i] : 0;
    a[t] = v;
    __syncthreads();
    int* in = a;
    int* out = b;
    for (int o = 1; o < 256; o <<= 1) {
        out[t] = in[t] + ((t >= o) ? in[t - o] : 0);
        __syncthreads();
        int* tmp = in; in = out; out = tmp;
    }
    if (i < N) row_start[i] = boffs[blockIdx.x] + in[t] - v;
}

__global__ void set_val_kernel(int* __restrict__ p, int v) { p[0] = v; }

// ---------------------------------------------------------------------------
// Per node (8/block): ft = x @ W (96 cols), el/er via al/ar dot.
// ---------------------------------------------------------------------------
__global__ void ft_elr_kernel(const void* __restrict__ X, int kind, const int* __restrict__ mode,
                              int din, const float* __restrict__ W,
                              const float* __restrict__ al, const float* __restrict__ ar,
                              float* __restrict__ ft, float* __restrict__ elr, int N) {
    __shared__ float xs[8 * 96];
    __shared__ float fs[8 * 96];
    int base = blockIdx.x * 8;
    int t = threadIdx.x;
    int m = *mode;
    for (int i = t; i < 8 * din; i += 256) {
        int ln = i / din, d = i - ln * din;
        int node = base + ln;
        float v = 0.f;
        if (node < N) {
            size_t idx = (size_t)node * din + d;
            if (kind == 1)   v = ((const float*)X)[idx];
            else if (m == 0) v = b2f(((const bf16*)X)[idx]);
            else             v = ((const float*)X)[idx];
        }
        xs[ln * 96 + d] = v;
    }
    __syncthreads();
    for (int i = t; i < 768; i += 256) {
        int ln = i / 96, c = i - ln * 96;
        int node = base + ln;
        float acc = 0.f;
        const float* xr = xs + ln * 96;
        for (int d = 0; d < din; ++d) acc += xr[d] * W[d * 96 + c];
        fs[ln * 96 + c] = acc;
        if (node < N) ft[(size_t)node * 96 + c] = acc;
    }
    __syncthreads();
    if (t < 48) {
        int ln = t / 6, q = t - ln * 6;
        int h = q >> 1, isr = q & 1;
        int node = base + ln;
        if (node < N) {
            const float* av = isr ? ar : al;
            const float* fr = fs + ln * 96 + h * 32;
            float acc = 0.f;
            for (int f = 0; f < 32; ++f) acc += fr[f] * av[h * 32 + f];
            elr[node * 6 + isr * 3 + h] = acc;
        }
    }
}

// ---------------------------------------------------------------------------
// Fused scatter + edge pass (both layers' edge-feature math in ONE sequential
// sweep over efeats).  Per edge e (original order):
//   - sequential 64B efeats row load (perfect coalescing)
//   - ee1/ee2 = ef . wae1/wae2   (3 heads each)
//   - ex1 = exp(leakyrelu(el1[src] + er1[dst] + ee1))   (elr1 ready, L2-hot)
//   - ONE random 32B struct write to the CSR slot: {src, ex1*3, ee2*3, pad}
// This touches 1 cache line per edge instead of 3 (old scatter), kills the
// csr_edges/csr_dst arrays, the ex round-trip, and the second (random) read
// of efeats entirely.
// ---------------------------------------------------------------------------
__global__ void scatter_edge_kernel(const void* __restrict__ ef, const int* __restrict__ mode,
                                    const float* __restrict__ wae1, const float* __restrict__ wae2,
                                    const int* __restrict__ src, const int* __restrict__ dst,
                                    const float* __restrict__ elr,
                                    const int* __restrict__ row_start, int* __restrict__ cur,
                                    float4* __restrict__ S, int E) {
    __shared__ float w1[96];
    __shared__ float w2[96];
    int t = threadIdx.x;
    if (t < 96) { w1[t] = wae1[t]; w2[t] = wae2[t]; }
    __syncthreads();
    int e = blockIdx.x * blockDim.x + t;
    if (e >= E) return;
    int m = *mode;

    float x[32];
    if (m == 0) {
        const uint4* p = (const uint4*)((const uint16_t*)ef + (size_t)e * 32);
#pragma unroll
        for (int q = 0; q < 4; ++q) {
            uint4 u = p[q];
            x[q * 8 + 0] = bits2f(u.x << 16); x[q * 8 + 1] = bits2f(u.x & 0xffff0000u);
            x[q * 8 + 2] = bits2f(u.y << 16); x[q * 8 + 3] = bits2f(u.y & 0xffff0000u);
            x[q * 8 + 4] = bits2f(u.z << 16); x[q * 8 + 5] = bits2f(u.z & 0xffff0000u);
            x[q * 8 + 6] = bits2f(u.w << 16); x[q * 8 + 7] = bits2f(u.w & 0xffff0000u);
        }
    } else {
        const float4* p = (const float4*)((const float*)ef + (size_t)e * 32);
#pragma unroll
        for (int q = 0; q < 8; ++q) {
            float4 u = p[q];
            x[q * 4 + 0] = u.x; x[q * 4 + 1] = u.y; x[q * 4 + 2] = u.z; x[q * 4 + 3] = u.w;
        }
    }
    float a0 = 0.f, a1 = 0.f, a2 = 0.f;   // ee1
    float c0 = 0.f, c1 = 0.f, c2 = 0.f;   // ee2
#pragma unroll
    for (int d = 0; d < 32; ++d) {
        float xv = x[d];
        a0 += xv * w1[d * 3 + 0];
        a1 += xv * w1[d * 3 + 1];
        a2 += xv * w1[d * 3 + 2];
        c0 += xv * w2[d * 3 + 0];
        c1 += xv * w2[d * 3 + 1];
        c2 += xv * w2[d * 3 + 2];
    }
    int si = src[e], di = dst[e];
    float2 el01 = *(const float2*)(elr + si * 6);
    float  el2  = elr[si * 6 + 2];
    float2 er01 = *(const float2*)(elr + di * 6 + 3);  // hmm: si*6+3 is 4-aligned only
    // NOTE: elr + di*6 + 3 is only 4-byte aligned; use scalar loads for er.
    float er0 = elr[di * 6 + 3], er1 = elr[di * 6 + 4], er2 = elr[di * 6 + 5];
    (void)er01;
    float l0 = el01.x + er0 + a0;
    float l1 = el01.y + er1 + a1;
    float l2 = el2    + er2 + a2;
    l0 = (l0 > 0.f) ? l0 : 0.2f * l0;
    l1 = (l1 > 0.f) ? l1 : 0.2f * l1;
    l2 = (l2 > 0.f) ? l2 : 0.2f * l2;
    int p = atomicAdd(&cur[di], 1);
    int pos = row_start[di] + p;
    S[2 * pos]     = make_float4(__int_as_float(si), __expf(l0), __expf(l1), __expf(l2));
    S[2 * pos + 1] = make_float4(c0, c1, c2, 0.f);
}

// ---------------------------------------------------------------------------
// Layer-1 aggregation: ex1 sits pre-computed in the packed struct.
// 32 lanes per node; lane handles features lane, lane+32, lane+64.
// ---------------------------------------------------------------------------
__global__ void aggregate_direct_kernel(const float* __restrict__ ft, const float4* __restrict__ S,
                                        const int* __restrict__ row_start,
                                        const float* __restrict__ bias, int do_relu,
                                        float* __restrict__ R, int N) {
    int t = threadIdx.x;
    int node = blockIdx.x * 8 + (t >> 5);
    int lane = t & 31;
    if (node >= N) return;
    int beg = row_start[node], end = row_start[node + 1];
    float a0 = 0.f, a1 = 0.f, a2 = 0.f, s0 = 0.f, s1 = 0.f, s2 = 0.f;
    int i = beg;
    for (; i + 4 <= end; i += 4) {
        float4 q0 = S[2 * (i + 0)];
        float4 q1 = S[2 * (i + 1)];
        float4 q2 = S[2 * (i + 2)];
        float4 q3 = S[2 * (i + 3)];
        int v0 = __float_as_int(q0.x), v1 = __float_as_int(q1.x);
        int v2 = __float_as_int(q2.x), v3 = __float_as_int(q3.x);
        const float* f0 = ft + (size_t)v0 * 96;
        const float* f1 = ft + (size_t)v1 * 96;
        const float* f2 = ft + (size_t)v2 * 96;
        const float* f3 = ft + (size_t)v3 * 96;
        a0 += f0[lane] * q0.y + f1[lane] * q1.y + f2[lane] * q2.y + f3[lane] * q3.y;
        a1 += f0[lane + 32] * q0.z + f1[lane + 32] * q1.z + f2[lane + 32] * q2.z + f3[lane + 32] * q3.z;
        a2 += f0[lane + 64] * q0.w + f1[lane + 64] * q1.w + f2[lane + 64] * q2.w + f3[lane + 64] * q3.w;
        s0 += q0.y + q1.y + q2.y + q3.y;
        s1 += q0.z + q1.z + q2.z + q3.z;
        s2 += q0.w + q1.w + q2.w + q3.w;
    }
    for (; i < end; ++i) {
        float4 q = S[2 * i];
        int sv = __float_as_int(q.x);
        const float* fr = ft + (size_t)sv * 96;
        a0 += fr[lane] * q.y;
        a1 += fr[lane + 32] * q.z;
        a2 += fr[lane + 64] * q.w;
        s0 += q.y; s1 += q.z; s2 += q.w;
    }
    float r0, r1, r2;
    if (end > beg) { r0 = a0 / s0; r1 = a1 / s1; r2 = a2 / s2; }
    else           { r0 = r1 = r2 = 0.f; }
    r0 += bias[lane]; r1 += bias[lane + 32]; r2 += bias[lane + 64];
    if (do_relu) { r0 = fmaxf(r0, 0.f); r1 = fmaxf(r1, 0.f); r2 = fmaxf(r2, 0.f); }
    float* out = R + (size_t)node * 96;
    out[lane] = r0; out[lane + 32] = r1; out[lane + 64] = r2;
}

// ---------------------------------------------------------------------------
// Layer-2 aggregation with fused edge softmax: ex2 computed inline from the
// stored ee2 + elr2 (dst term hoisted once per node; exp redundant per lane
// is ~20 VALU ops/edge — negligible next to the ft gathers).
// ---------------------------------------------------------------------------
__global__ void aggregate_fused_kernel(const float* __restrict__ ft, const float4* __restrict__ S,
                                       const int* __restrict__ row_start,
                                       const float* __restrict__ elr,
                                       const float* __restrict__ bias,
                                       float* __restrict__ R, int N) {
    int t = threadIdx.x;
    int node = blockIdx.x * 8 + (t >> 5);
    int lane = t & 31;
    if (node >= N) return;
    int beg = row_start[node], end = row_start[node + 1];
    float er0 = elr[node * 6 + 3], er1 = elr[node * 6 + 4], er2 = elr[node * 6 + 5];
    float a0 = 0.f, a1 = 0.f, a2 = 0.f, s0 = 0.f, s1 = 0.f, s2 = 0.f;
    int i = beg;
    for (; i + 4 <= end; i += 4) {
#pragma unroll
        for (int u = 0; u < 4; ++u) {
            float4 qa = S[2 * (i + u)];
            float4 qb = S[2 * (i + u) + 1];
            int sv = __float_as_int(qa.x);
            float2 el01 = *(const float2*)(elr + sv * 6);
            float  el2  = elr[sv * 6 + 2];
            float l0 = el01.x + er0 + qb.x;
            float l1 = el01.y + er1 + qb.y;
            float l2 = el2    + er2 + qb.z;
            l0 = (l0 > 0.f) ? l0 : 0.2f * l0;
            l1 = (l1 > 0.f) ? l1 : 0.2f * l1;
            l2 = (l2 > 0.f) ? l2 : 0.2f * l2;
            float e0 = __expf(l0), e1 = __expf(l1), e2 = __expf(l2);
            const float* fr = ft + (size_t)sv * 96;
            a0 += fr[lane] * e0;
            a1 += fr[lane + 32] * e1;
            a2 += fr[lane + 64] * e2;
            s0 += e0; s1 += e1; s2 += e2;
        }
    }
    for (; i < end; ++i) {
        float4 qa = S[2 * i];
        float4 qb = S[2 * i + 1];
        int sv = __float_as_int(qa.x);
        float2 el01 = *(const float2*)(elr + sv * 6);
        float  el2  = elr[sv * 6 + 2];
        float l0 = el01.x + er0 + qb.x;
        float l1 = el01.y + er1 + qb.y;
        float l2 = el2    + er2 + qb.z;
        l0 = (l0 > 0.f) ? l0 : 0.2f * l0;
        l1 = (l1 > 0.f) ? l1 : 0.2f * l1;
        l2 = (l2 > 0.f) ? l2 : 0.2f * l2;
        float e0 = __expf(l0), e1 = __expf(l1), e2 = __expf(l2);
        const float* fr = ft + (size_t)sv * 96;
        a0 += fr[lane] * e0;
        a1 += fr[lane + 32] * e1;
        a2 += fr[lane + 64] * e2;
        s0 += e0; s1 += e1; s2 += e2;
    }
    float r0, r1, r2;
    if (end > beg) { r0 = a0 / s0; r1 = a1 / s1; r2 = a2 / s2; }
    else           { r0 = r1 = r2 = 0.f; }
    r0 += bias[lane]; r1 += bias[lane + 32]; r2 += bias[lane + 64];
    float* out = R + (size_t)node * 96;
    out[lane] = r0; out[lane + 32] = r1; out[lane + 64] = r2;
}

// Per node (8/block): u[n,c] = h@Wp[0:96,c] + bp[c]; v[n,c] = h@Wp[96:,c]
__global__ void uv_kernel(const float* __restrict__ h, const float* __restrict__ Wp,
                          const float* __restrict__ bp, float* __restrict__ uv, int N) {
    __shared__ float hs[8 * 96];
    int base = blockIdx.x * 8;
    int t = threadIdx.x;
    for (int i = t; i < 768; i += 256) {
        int ln = i / 96, c = i - ln * 96;
        int node = base + ln;
        hs[i] = (node < N) ? h[(size_t)node * 96 + c] : 0.f;
    }
    __syncthreads();
    if (t < 160) {
        int ln = t / 20, q = t - ln * 20;
        int half = q / 10, c = q - half * 10;
        int node = base + ln;
        if (node < N) {
            float acc = half ? 0.f : bp[c];
            const float* hr = hs + ln * 96;
            const float* wcol = Wp + half * 960 + c;
            for (int j = 0; j < 96; ++j) acc += hr[j] * wcol[j * 10];
            uv[node * 20 + q] = acc;
        }
    }
}

__global__ void score_kernel(const float* __restrict__ uv, const int* __restrict__ src,
                             const int* __restrict__ dst, const int* __restrict__ mode,
                             void* __restrict__ out, int E) {
    int e = blockIdx.x * blockDim.x + threadIdx.x;
    if (e >= E) return;
    int si = src[e], di = dst[e];
    const float* u = uv + (size_t)si * 20;
    const float* v = uv + (size_t)di * 20 + 10;
    float r[10];
#pragma unroll
    for (int c = 0; c < 10; ++c) r[c] = u[c] + v[c];
    if (*mode == 0) {
        bf16 o[10];
#pragma unroll
        for (int c = 0; c < 10; ++c) o[c] = __float2bfloat16(r[c]);
        uint32_t* po = (uint32_t*)((bf16*)out + (size_t)e * 10);
        const uint32_t* ps = (const uint32_t*)o;
#pragma unroll
        for (int q = 0; q < 5; ++q) po[q] = ps[q];
    } else {
        float2* po = (float2*)((float*)out + (size_t)e * 10);
#pragma unroll
        for (int q = 0; q < 5; ++q) po[q] = make_float2(r[2 * q], r[2 * q + 1]);
    }
}

extern "C" void kernel_launch(void* const* d_in, const int* in_sizes, int n_in,
                              void* d_out, int out_size, void* d_ws, size_t ws_size,
                              hipStream_t stream) {
    const void* nfeats = d_in[0];
    const void* efeats = d_in[1];
    const int* src = (const int*)d_in[2];
    const int* dst = (const int*)d_in[3];

    const int N = in_sizes[0] / 64;
    const int E = in_sizes[2];

    // ---- workspace (~131 MB) ----
    char* w = (char*)d_ws;
    auto alloc = [&](size_t bytes) {
        void* p = (void*)w;
        w += (bytes + 255) & ~(size_t)255;
        return p;
    };
    int*    flag      = (int*)alloc(256);
    float*  pbuf      = (float*)alloc((size_t)24202 * 4);
    float*  wae1      = (float*)alloc(96 * 4);
    float*  wae2      = (float*)alloc(96 * 4);
    float*  R         = (float*)alloc((size_t)N * 96 * 4);   // h (aggregate out)
    float*  F         = (float*)alloc((size_t)N * 96 * 4);   // ft per layer
    float4* S         = (float4*)alloc((size_t)E * 32);      // {src, ex1*3, ee2*3, pad}
    float*  elr       = (float*)alloc((size_t)N * 6 * 4);
    int*    row_start = (int*)alloc((size_t)(N + 1) * 4);
    int*    cnt       = (int*)alloc((size_t)N * 4);
    int*    bsums     = (int*)alloc(512 * 4);
    float*  uv        = (float*)S;                            // S dead after layer 2

    const int ns[14] = {64*96, 32*96, 96, 96, 96, 96, 96*96, 32*96, 96, 96, 96, 96, 192*10, 10};
    ParamTable T;
    int off = 0;
    for (int k = 0; k < 14; ++k) { T.src[k] = d_in[4 + k]; T.off[k] = off; off += ns[k]; }
    T.off[14] = off;
    float* W1f  = pbuf + T.off[0];
    float* We1f = pbuf + T.off[1];
    float* al1f = pbuf + T.off[2];
    float* ar1f = pbuf + T.off[3];
    float* ae1f = pbuf + T.off[4];
    float* b1f  = pbuf + T.off[5];
    float* W2f  = pbuf + T.off[6];
    float* We2f = pbuf + T.off[7];
    float* al2f = pbuf + T.off[8];
    float* ar2f = pbuf + T.off[9];
    float* ae2f = pbuf + T.off[10];
    float* b2f_ = pbuf + T.off[11];
    float* Wpf  = pbuf + T.off[12];
    float* bpf  = pbuf + T.off[13];

    dim3 b256(256);
    int eblocks    = (E + 255) / 256;
    int nodeBlocks = (N + 7) / 8;
    int nb         = (N + 255) / 256;

    hipLaunchKernelGGL(detect_mode_kernel, dim3(1), dim3(64), 0, stream,
                       (const uint16_t*)nfeats, flag);
    hipLaunchKernelGGL(convert_params_kernel, dim3((off + 255) / 256), b256, 0, stream,
                       T, flag, pbuf);
    hipLaunchKernelGGL(fold_wae_kernel, dim3(1), dim3(128), 0, stream, We1f, ae1f, wae1);
    hipLaunchKernelGGL(fold_wae_kernel, dim3(1), dim3(128), 0, stream, We2f, ae2f, wae2);

    // ---- CSR offsets ----
    hipMemsetAsync(cnt, 0, (size_t)N * 4, stream);
    hipLaunchKernelGGL(hist_kernel, dim3(eblocks), b256, 0, stream, dst, cnt, E);
    hipLaunchKernelGGL(block_sum_kernel, dim3(nb), b256, 0, stream, cnt, bsums, N);
    hipLaunchKernelGGL(scan_bsums_kernel, dim3(1), dim3(512), 0, stream, bsums, nb);
    hipLaunchKernelGGL(scan_expand_kernel, dim3(nb), b256, 0, stream, cnt, bsums, row_start, N);
    hipLaunchKernelGGL(set_val_kernel, dim3(1), dim3(1), 0, stream, row_start + N, E);

    // ---- layer-1 node transform (needed by fused scatter) ----
    hipLaunchKernelGGL(ft_elr_kernel, dim3(nodeBlocks), b256, 0, stream,
                       nfeats, 0, flag, 64, W1f, al1f, ar1f, F, elr, N);

    // ---- fused scatter + both layers' edge-feature math (ONE efeats sweep) ----
    hipMemsetAsync(cnt, 0, (size_t)N * 4, stream);
    hipLaunchKernelGGL(scatter_edge_kernel, dim3(eblocks), b256, 0, stream,
                       efeats, flag, wae1, wae2, src, dst, elr, row_start, cnt, S, E);

    // ---- layer 1 aggregate ----
    hipLaunchKernelGGL(aggregate_direct_kernel, dim3(nodeBlocks), b256, 0, stream,
                       F, S, row_start, b1f, 1, R, N);

    // ---- layer 2 ----
    hipLaunchKernelGGL(ft_elr_kernel, dim3(nodeBlocks), b256, 0, stream,
                       (const void*)R, 1, flag, 96, W2f, al2f, ar2f, F, elr, N);
    hipLaunchKernelGGL(aggregate_fused_kernel, dim3(nodeBlocks), b256, 0, stream,
                       F, S, row_start, elr, b2f_, R, N);

    // ---- predictor ----
    hipLaunchKernelGGL(uv_kernel, dim3(nodeBlocks), b256, 0, stream, R, Wpf, bpf, uv, N);
    hipLaunchKernelGGL(score_kernel, dim3(eblocks), b256, 0, stream,
                       uv, src, dst, flag, d_out, E);
}

// Round 2
// 1091.565 us; speedup vs baseline: 1.0943x; 1.0069x over previous
//
#include <hip/hip_runtime.h>
#include <hip/hip_bf16.h>
#include <stdint.h>

typedef __hip_bfloat16 bf16;

__device__ __forceinline__ float b2f(bf16 x) { return __bfloat162float(x); }
__device__ __forceinline__ float bits2f(uint32_t u) {
    union { uint32_t i; float f; } c; c.i = u; return c.f;
}

// ---------------------------------------------------------------------------
// Mode detection: 0 = bf16 external tensors, 1 = f32.
// ---------------------------------------------------------------------------
__global__ void detect_mode_kernel(const uint16_t* __restrict__ nf, int* __restrict__ flag) {
    if (threadIdx.x != 0 || blockIdx.x != 0) return;
    int sane = 0;
    for (int i = 0; i < 256; ++i) {
        uint32_t u = nf[2 * i];
        float a = fabsf(bits2f(u << 16));
        if (a == 0.f || (a > 1e-5f && a < 100.f)) ++sane;
    }
    flag[0] = (sane >= 128) ? 0 : 1;
}

struct ParamTable {
    const void* src[14];
    int off[15];
};

__global__ void convert_params_kernel(ParamTable T, const int* __restrict__ mode,
                                      float* __restrict__ out) {
    int i = blockIdx.x * blockDim.x + threadIdx.x;
    if (i >= T.off[14]) return;
    int k = 0;
    while (k < 13 && i >= T.off[k + 1]) ++k;
    int j = i - T.off[k];
    out[i] = (*mode == 0) ? b2f(((const bf16*)T.src[k])[j]) : ((const float*)T.src[k])[j];
}

// wae[d*3+h] = sum_f We[d*96 + h*32 + f] * ae[h*32 + f]
__global__ void fold_wae_kernel(const float* __restrict__ We, const float* __restrict__ ae,
                                float* __restrict__ wae) {
    int t = threadIdx.x;
    if (t >= 96) return;
    int d = t / 3, h = t - d * 3;
    float acc = 0.f;
    for (int f = 0; f < 32; ++f) acc += We[d * 96 + h * 32 + f] * ae[h * 32 + f];
    wae[t] = acc;
}

// ---------------------------------------------------------------------------
// CSR build: histogram (also records per-edge rank) -> scan.
// rank[e] = arrival order of edge e within its dst bucket; scatter then needs
// no atomic at all (pos = row_start[dst] + rank).
// ---------------------------------------------------------------------------
__global__ void hist_rank_kernel(const int* __restrict__ dst, int* __restrict__ cnt,
                                 int* __restrict__ rank, int E) {
    int e = blockIdx.x * blockDim.x + threadIdx.x;
    if (e < E) rank[e] = atomicAdd(&cnt[dst[e]], 1);
}

__global__ void block_sum_kernel(const int* __restrict__ deg, int* __restrict__ bsums, int N) {
    __shared__ int sd[256];
    int t = threadIdx.x;
    int i = blockIdx.x * 256 + t;
    sd[t] = (i < N) ? deg[i] : 0;
    __syncthreads();
    for (int o = 128; o > 0; o >>= 1) {
        if (t < o) sd[t] += sd[t + o];
        __syncthreads();
    }
    if (t == 0) bsums[blockIdx.x] = sd[0];
}

__global__ void scan_bsums_kernel(int* __restrict__ bsums, int nb) {
    __shared__ int a[512], b[512];
    int t = threadIdx.x;
    int v = (t < nb) ? bsums[t] : 0;
    a[t] = v;
    __syncthreads();
    int* in = a;
    int* out = b;
    for (int o = 1; o < 512; o <<= 1) {
        out[t] = in[t] + ((t >= o) ? in[t - o] : 0);
        __syncthreads();
        int* tmp = in; in = out; out = tmp;
    }
    if (t < nb) bsums[t] = in[t] - v;
}

__global__ void scan_expand_kernel(const int* __restrict__ deg, const int* __restrict__ boffs,
                                   int* __restrict__ row_start, int N) {
    __shared__ int a[256], b[256];
    int t = threadIdx.x;
    int i = blockIdx.x * 256 + t;
    int v = (i < N) ? deg[i] : 0;
    a[t] = v;
    __syncthreads();
    int* in = a;
    int* out = b;
    for (int o = 1; o < 256; o <<= 1) {
        out[t] = in[t] + ((t >= o) ? in[t - o] : 0);
        __syncthreads();
        int* tmp = in; in = out; out = tmp;
    }
    if (i < N) row_start[i] = boffs[blockIdx.x] + in[t] - v;
}

__global__ void set_val_kernel(int* __restrict__ p, int v) { p[0] = v; }

// ---------------------------------------------------------------------------
// Per node (8/block): ft = x @ W (96 cols), el/er via al/ar dot.
// ---------------------------------------------------------------------------
__global__ void ft_elr_kernel(const void* __restrict__ X, int kind, const int* __restrict__ mode,
                              int din, const float* __restrict__ W,
                              const float* __restrict__ al, const float* __restrict__ ar,
                              float* __restrict__ ft, float* __restrict__ elr, int N) {
    __shared__ float xs[8 * 96];
    __shared__ float fs[8 * 96];
    int base = blockIdx.x * 8;
    int t = threadIdx.x;
    int m = *mode;
    for (int i = t; i < 8 * din; i += 256) {
        int ln = i / din, d = i - ln * din;
        int node = base + ln;
        float v = 0.f;
        if (node < N) {
            size_t idx = (size_t)node * din + d;
            if (kind == 1)   v = ((const float*)X)[idx];
            else if (m == 0) v = b2f(((const bf16*)X)[idx]);
            else             v = ((const float*)X)[idx];
        }
        xs[ln * 96 + d] = v;
    }
    __syncthreads();
    for (int i = t; i < 768; i += 256) {
        int ln = i / 96, c = i - ln * 96;
        int node = base + ln;
        float acc = 0.f;
        const float* xr = xs + ln * 96;
        for (int d = 0; d < din; ++d) acc += xr[d] * W[d * 96 + c];
        fs[ln * 96 + c] = acc;
        if (node < N) ft[(size_t)node * 96 + c] = acc;
    }
    __syncthreads();
    if (t < 48) {
        int ln = t / 6, q = t - ln * 6;
        int h = q >> 1, isr = q & 1;
        int node = base + ln;
        if (node < N) {
            const float* av = isr ? ar : al;
            const float* fr = fs + ln * 96 + h * 32;
            float acc = 0.f;
            for (int f = 0; f < 32; ++f) acc += fr[f] * av[h * 32 + f];
            elr[node * 6 + isr * 3 + h] = acc;
        }
    }
}

// ---------------------------------------------------------------------------
// Fused scatter + both layers' edge-feature dots in ONE sequential sweep over
// efeats.  Pure streaming: no atomics (rank precomputed by hist), no elr
// reads (softmax deferred to the aggregates).  Per edge e (original order):
//   - sequential 64B efeats row load (perfect coalescing)
//   - ee1/ee2 = ef . wae1/wae2   (3 heads each)
//   - ONE random 32B struct write to the CSR slot: {src, ee1*3, ee2*3, pad}
// ---------------------------------------------------------------------------
__global__ void scatter_edge_kernel(const void* __restrict__ ef, const int* __restrict__ mode,
                                    const float* __restrict__ wae1, const float* __restrict__ wae2,
                                    const int* __restrict__ src, const int* __restrict__ dst,
                                    const int* __restrict__ rank,
                                    const int* __restrict__ row_start,
                                    float4* __restrict__ S, int E) {
    __shared__ float w1[96];
    __shared__ float w2[96];
    int t = threadIdx.x;
    if (t < 96) { w1[t] = wae1[t]; w2[t] = wae2[t]; }
    __syncthreads();
    int e = blockIdx.x * blockDim.x + t;
    if (e >= E) return;
    int m = *mode;

    float x[32];
    if (m == 0) {
        const uint4* p = (const uint4*)((const uint16_t*)ef + (size_t)e * 32);
#pragma unroll
        for (int q = 0; q < 4; ++q) {
            uint4 u = p[q];
            x[q * 8 + 0] = bits2f(u.x << 16); x[q * 8 + 1] = bits2f(u.x & 0xffff0000u);
            x[q * 8 + 2] = bits2f(u.y << 16); x[q * 8 + 3] = bits2f(u.y & 0xffff0000u);
            x[q * 8 + 4] = bits2f(u.z << 16); x[q * 8 + 5] = bits2f(u.z & 0xffff0000u);
            x[q * 8 + 6] = bits2f(u.w << 16); x[q * 8 + 7] = bits2f(u.w & 0xffff0000u);
        }
    } else {
        const float4* p = (const float4*)((const float*)ef + (size_t)e * 32);
#pragma unroll
        for (int q = 0; q < 8; ++q) {
            float4 u = p[q];
            x[q * 4 + 0] = u.x; x[q * 4 + 1] = u.y; x[q * 4 + 2] = u.z; x[q * 4 + 3] = u.w;
        }
    }
    float a0 = 0.f, a1 = 0.f, a2 = 0.f;   // ee1
    float c0 = 0.f, c1 = 0.f, c2 = 0.f;   // ee2
#pragma unroll
    for (int d = 0; d < 32; ++d) {
        float xv = x[d];
        a0 += xv * w1[d * 3 + 0];
        a1 += xv * w1[d * 3 + 1];
        a2 += xv * w1[d * 3 + 2];
        c0 += xv * w2[d * 3 + 0];
        c1 += xv * w2[d * 3 + 1];
        c2 += xv * w2[d * 3 + 2];
    }
    int si = src[e], di = dst[e];
    int pos = row_start[di] + rank[e];
    S[2 * pos]     = make_float4(__int_as_float(si), a0, a1, a2);
    S[2 * pos + 1] = make_float4(c0, c1, c2, 0.f);
}

// ---------------------------------------------------------------------------
// Aggregation with fused edge softmax (both layers).  Per edge:
//   ex = exp(leakyrelu(el[src] + er[node] + ee))     ee from qa (L1) or qb (L2)
// er hoisted once per node; el[sv] is a broadcast load co-indexed with ft[sv].
// 32 lanes per node; lane handles features lane, lane+32, lane+64.
// ---------------------------------------------------------------------------
__global__ void aggregate_kernel(const float* __restrict__ ft, const float4* __restrict__ S,
                                 const int* __restrict__ row_start,
                                 const float* __restrict__ elr,
                                 const float* __restrict__ bias,
                                 int use_qa, int do_relu,
                                 float* __restrict__ R, int N) {
    int t = threadIdx.x;
    int node = blockIdx.x * 8 + (t >> 5);
    int lane = t & 31;
    if (node >= N) return;
    int beg = row_start[node], end = row_start[node + 1];
    float er0 = elr[node * 6 + 3], er1 = elr[node * 6 + 4], er2 = elr[node * 6 + 5];
    float a0 = 0.f, a1 = 0.f, a2 = 0.f, s0 = 0.f, s1 = 0.f, s2 = 0.f;
    int i = beg;
    for (; i + 4 <= end; i += 4) {
#pragma unroll
        for (int u = 0; u < 4; ++u) {
            float4 qa = S[2 * (i + u)];
            float4 qb = S[2 * (i + u) + 1];
            int sv = __float_as_int(qa.x);
            float ee0, ee1, ee2;
            if (use_qa) { ee0 = qa.y; ee1 = qa.z; ee2 = qa.w; }
            else        { ee0 = qb.x; ee1 = qb.y; ee2 = qb.z; }
            float2 el01 = *(const float2*)(elr + sv * 6);
            float  el2  = elr[sv * 6 + 2];
            float l0 = el01.x + er0 + ee0;
            float l1 = el01.y + er1 + ee1;
            float l2 = el2    + er2 + ee2;
            l0 = (l0 > 0.f) ? l0 : 0.2f * l0;
            l1 = (l1 > 0.f) ? l1 : 0.2f * l1;
            l2 = (l2 > 0.f) ? l2 : 0.2f * l2;
            float e0 = __expf(l0), e1 = __expf(l1), e2 = __expf(l2);
            const float* fr = ft + (size_t)sv * 96;
            a0 += fr[lane] * e0;
            a1 += fr[lane + 32] * e1;
            a2 += fr[lane + 64] * e2;
            s0 += e0; s1 += e1; s2 += e2;
        }
    }
    for (; i < end; ++i) {
        float4 qa = S[2 * i];
        float4 qb = S[2 * i + 1];
        int sv = __float_as_int(qa.x);
        float ee0, ee1, ee2;
        if (use_qa) { ee0 = qa.y; ee1 = qa.z; ee2 = qa.w; }
        else        { ee0 = qb.x; ee1 = qb.y; ee2 = qb.z; }
        float2 el01 = *(const float2*)(elr + sv * 6);
        float  el2  = elr[sv * 6 + 2];
        float l0 = el01.x + er0 + ee0;
        float l1 = el01.y + er1 + ee1;
        float l2 = el2    + er2 + ee2;
        l0 = (l0 > 0.f) ? l0 : 0.2f * l0;
        l1 = (l1 > 0.f) ? l1 : 0.2f * l1;
        l2 = (l2 > 0.f) ? l2 : 0.2f * l2;
        float e0 = __expf(l0), e1 = __expf(l1), e2 = __expf(l2);
        const float* fr = ft + (size_t)sv * 96;
        a0 += fr[lane] * e0;
        a1 += fr[lane + 32] * e1;
        a2 += fr[lane + 64] * e2;
        s0 += e0; s1 += e1; s2 += e2;
    }
    float r0, r1, r2;
    if (end > beg) { r0 = a0 / s0; r1 = a1 / s1; r2 = a2 / s2; }
    else           { r0 = r1 = r2 = 0.f; }
    r0 += bias[lane]; r1 += bias[lane + 32]; r2 += bias[lane + 64];
    if (do_relu) { r0 = fmaxf(r0, 0.f); r1 = fmaxf(r1, 0.f); r2 = fmaxf(r2, 0.f); }
    float* out = R + (size_t)node * 96;
    out[lane] = r0; out[lane + 32] = r1; out[lane + 64] = r2;
}

// Per node (8/block): u[n,c] = h@Wp[0:96,c] + bp[c]; v[n,c] = h@Wp[96:,c]
__global__ void uv_kernel(const float* __restrict__ h, const float* __restrict__ Wp,
                          const float* __restrict__ bp, float* __restrict__ uv, int N) {
    __shared__ float hs[8 * 96];
    int base = blockIdx.x * 8;
    int t = threadIdx.x;
    for (int i = t; i < 768; i += 256) {
        int ln = i / 96, c = i - ln * 96;
        int node = base + ln;
        hs[i] = (node < N) ? h[(size_t)node * 96 + c] : 0.f;
    }
    __syncthreads();
    if (t < 160) {
        int ln = t / 20, q = t - ln * 20;
        int half = q / 10, c = q - half * 10;
        int node = base + ln;
        if (node < N) {
            float acc = half ? 0.f : bp[c];
            const float* hr = hs + ln * 96;
            const float* wcol = Wp + half * 960 + c;
            for (int j = 0; j < 96; ++j) acc += hr[j] * wcol[j * 10];
            uv[node * 20 + q] = acc;
        }
    }
}

__global__ void score_kernel(const float* __restrict__ uv, const int* __restrict__ src,
                             const int* __restrict__ dst, const int* __restrict__ mode,
                             void* __restrict__ out, int E) {
    int e = blockIdx.x * blockDim.x + threadIdx.x;
    if (e >= E) return;
    int si = src[e], di = dst[e];
    const float* u = uv + (size_t)si * 20;
    const float* v = uv + (size_t)di * 20 + 10;
    float r[10];
#pragma unroll
    for (int c = 0; c < 10; ++c) r[c] = u[c] + v[c];
    if (*mode == 0) {
        bf16 o[10];
#pragma unroll
        for (int c = 0; c < 10; ++c) o[c] = __float2bfloat16(r[c]);
        uint32_t* po = (uint32_t*)((bf16*)out + (size_t)e * 10);
        const uint32_t* ps = (const uint32_t*)o;
#pragma unroll
        for (int q = 0; q < 5; ++q) po[q] = ps[q];
    } else {
        float2* po = (float2*)((float*)out + (size_t)e * 10);
#pragma unroll
        for (int q = 0; q < 5; ++q) po[q] = make_float2(r[2 * q], r[2 * q + 1]);
    }
}

extern "C" void kernel_launch(void* const* d_in, const int* in_sizes, int n_in,
                              void* d_out, int out_size, void* d_ws, size_t ws_size,
                              hipStream_t stream) {
    const void* nfeats = d_in[0];
    const void* efeats = d_in[1];
    const int* src = (const int*)d_in[2];
    const int* dst = (const int*)d_in[3];

    const int N = in_sizes[0] / 64;
    const int E = in_sizes[2];

    // ---- workspace (~138 MB) ----
    char* w = (char*)d_ws;
    auto alloc = [&](size_t bytes) {
        void* p = (void*)w;
        w += (bytes + 255) & ~(size_t)255;
        return p;
    };
    int*    flag      = (int*)alloc(256);
    float*  pbuf      = (float*)alloc((size_t)24202 * 4);
    float*  wae1      = (float*)alloc(96 * 4);
    float*  wae2      = (float*)alloc(96 * 4);
    float*  R         = (float*)alloc((size_t)N * 96 * 4);   // h (aggregate out)
    float*  F         = (float*)alloc((size_t)N * 96 * 4);   // ft per layer
    float4* S         = (float4*)alloc((size_t)E * 32);      // {src, ee1*3}{ee2*3, pad}
    float*  elr       = (float*)alloc((size_t)N * 6 * 4);
    int*    row_start = (int*)alloc((size_t)(N + 1) * 4);
    int*    cnt       = (int*)alloc((size_t)N * 4);
    int*    bsums     = (int*)alloc(512 * 4);
    int*    rank      = (int*)alloc((size_t)E * 4);
    float*  uv        = (float*)S;                            // S dead after layer 2

    const int ns[14] = {64*96, 32*96, 96, 96, 96, 96, 96*96, 32*96, 96, 96, 96, 96, 192*10, 10};
    ParamTable T;
    int off = 0;
    for (int k = 0; k < 14; ++k) { T.src[k] = d_in[4 + k]; T.off[k] = off; off += ns[k]; }
    T.off[14] = off;
    float* W1f  = pbuf + T.off[0];
    float* We1f = pbuf + T.off[1];
    float* al1f = pbuf + T.off[2];
    float* ar1f = pbuf + T.off[3];
    float* ae1f = pbuf + T.off[4];
    float* b1f  = pbuf + T.off[5];
    float* W2f  = pbuf + T.off[6];
    float* We2f = pbuf + T.off[7];
    float* al2f = pbuf + T.off[8];
    float* ar2f = pbuf + T.off[9];
    float* ae2f = pbuf + T.off[10];
    float* b2f_ = pbuf + T.off[11];
    float* Wpf  = pbuf + T.off[12];
    float* bpf  = pbuf + T.off[13];

    dim3 b256(256);
    int eblocks    = (E + 255) / 256;
    int nodeBlocks = (N + 7) / 8;
    int nb         = (N + 255) / 256;

    hipLaunchKernelGGL(detect_mode_kernel, dim3(1), dim3(64), 0, stream,
                       (const uint16_t*)nfeats, flag);
    hipLaunchKernelGGL(convert_params_kernel, dim3((off + 255) / 256), b256, 0, stream,
                       T, flag, pbuf);
    hipLaunchKernelGGL(fold_wae_kernel, dim3(1), dim3(128), 0, stream, We1f, ae1f, wae1);
    hipLaunchKernelGGL(fold_wae_kernel, dim3(1), dim3(128), 0, stream, We2f, ae2f, wae2);

    // ---- CSR offsets + per-edge rank ----
    hipMemsetAsync(cnt, 0, (size_t)N * 4, stream);
    hipLaunchKernelGGL(hist_rank_kernel, dim3(eblocks), b256, 0, stream, dst, cnt, rank, E);
    hipLaunchKernelGGL(block_sum_kernel, dim3(nb), b256, 0, stream, cnt, bsums, N);
    hipLaunchKernelGGL(scan_bsums_kernel, dim3(1), dim3(512), 0, stream, bsums, nb);
    hipLaunchKernelGGL(scan_expand_kernel, dim3(nb), b256, 0, stream, cnt, bsums, row_start, N);
    hipLaunchKernelGGL(set_val_kernel, dim3(1), dim3(1), 0, stream, row_start + N, E);

    // ---- fused scatter + both layers' edge-feature dots (ONE efeats sweep) ----
    hipLaunchKernelGGL(scatter_edge_kernel, dim3(eblocks), b256, 0, stream,
                       efeats, flag, wae1, wae2, src, dst, rank, row_start, S, E);

    // ---- layer 1 ----
    hipLaunchKernelGGL(ft_elr_kernel, dim3(nodeBlocks), b256, 0, stream,
                       nfeats, 0, flag, 64, W1f, al1f, ar1f, F, elr, N);
    hipLaunchKernelGGL(aggregate_kernel, dim3(nodeBlocks), b256, 0, stream,
                       F, S, row_start, elr, b1f, 1, 1, R, N);

    // ---- layer 2 ----
    hipLaunchKernelGGL(ft_elr_kernel, dim3(nodeBlocks), b256, 0, stream,
                       (const void*)R, 1, flag, 96, W2f, al2f, ar2f, F, elr, N);
    hipLaunchKernelGGL(aggregate_kernel, dim3(nodeBlocks), b256, 0, stream,
                       F, S, row_start, elr, b2f_, 0, 0, R, N);

    // ---- predictor ----
    hipLaunchKernelGGL(uv_kernel, dim3(nodeBlocks), b256, 0, stream, R, Wpf, bpf, uv, N);
    hipLaunchKernelGGL(score_kernel, dim3(eblocks), b256, 0, stream,
                       uv, src, dst, flag, d_out, E);
}

// Round 3
// 1030.496 us; speedup vs baseline: 1.1592x; 1.0593x over previous
//
#include <hip/hip_runtime.h>
#include <hip/hip_bf16.h>
#include <stdint.h>

typedef __hip_bfloat16 bf16;

__device__ __forceinline__ float b2f(bf16 x) { return __bfloat162float(x); }
__device__ __forceinline__ float bits2f(uint32_t u) {
    union { uint32_t i; float f; } c; c.i = u; return c.f;
}

// ---------------------------------------------------------------------------
// Mode detection: 0 = bf16 external tensors, 1 = f32.
// ---------------------------------------------------------------------------
__global__ void detect_mode_kernel(const uint16_t* __restrict__ nf, int* __restrict__ flag) {
    if (threadIdx.x != 0 || blockIdx.x != 0) return;
    int sane = 0;
    for (int i = 0; i < 256; ++i) {
        uint32_t u = nf[2 * i];
        float a = fabsf(bits2f(u << 16));
        if (a == 0.f || (a > 1e-5f && a < 100.f)) ++sane;
    }
    flag[0] = (sane >= 128) ? 0 : 1;
}

struct ParamTable {
    const void* src[14];
    int off[15];
};

__global__ void convert_params_kernel(ParamTable T, const int* __restrict__ mode,
                                      float* __restrict__ out) {
    int i = blockIdx.x * blockDim.x + threadIdx.x;
    if (i >= T.off[14]) return;
    int k = 0;
    while (k < 13 && i >= T.off[k + 1]) ++k;
    int j = i - T.off[k];
    out[i] = (*mode == 0) ? b2f(((const bf16*)T.src[k])[j]) : ((const float*)T.src[k])[j];
}

// wae[d*3+h] = sum_f We[d*96 + h*32 + f] * ae[h*32 + f]
__global__ void fold_wae_kernel(const float* __restrict__ We, const float* __restrict__ ae,
                                float* __restrict__ wae) {
    int t = threadIdx.x;
    if (t >= 96) return;
    int d = t / 3, h = t - d * 3;
    float acc = 0.f;
    for (int f = 0; f < 32; ++f) acc += We[d * 96 + h * 32 + f] * ae[h * 32 + f];
    wae[t] = acc;
}

// ---------------------------------------------------------------------------
// CSR build: histogram (also records per-edge rank) -> scan.
// ---------------------------------------------------------------------------
__global__ void hist_rank_kernel(const int* __restrict__ dst, int* __restrict__ cnt,
                                 int* __restrict__ rank, int E) {
    int e = blockIdx.x * blockDim.x + threadIdx.x;
    if (e < E) rank[e] = atomicAdd(&cnt[dst[e]], 1);
}

__global__ void block_sum_kernel(const int* __restrict__ deg, int* __restrict__ bsums, int N) {
    __shared__ int sd[256];
    int t = threadIdx.x;
    int i = blockIdx.x * 256 + t;
    sd[t] = (i < N) ? deg[i] : 0;
    __syncthreads();
    for (int o = 128; o > 0; o >>= 1) {
        if (t < o) sd[t] += sd[t + o];
        __syncthreads();
    }
    if (t == 0) bsums[blockIdx.x] = sd[0];
}

__global__ void scan_bsums_kernel(int* __restrict__ bsums, int nb) {
    __shared__ int a[512], b[512];
    int t = threadIdx.x;
    int v = (t < nb) ? bsums[t] : 0;
    a[t] = v;
    __syncthreads();
    int* in = a;
    int* out = b;
    for (int o = 1; o < 512; o <<= 1) {
        out[t] = in[t] + ((t >= o) ? in[t - o] : 0);
        __syncthreads();
        int* tmp = in; in = out; out = tmp;
    }
    if (t < nb) bsums[t] = in[t] - v;
}

__global__ void scan_expand_kernel(const int* __restrict__ deg, const int* __restrict__ boffs,
                                   int* __restrict__ row_start, int N) {
    __shared__ int a[256], b[256];
    int t = threadIdx.x;
    int i = blockIdx.x * 256 + t;
    int v = (i < N) ? deg[i] : 0;
    a[t] = v;
    __syncthreads();
    int* in = a;
    int* out = b;
    for (int o = 1; o < 256; o <<= 1) {
        out[t] = in[t] + ((t >= o) ? in[t - o] : 0);
        __syncthreads();
        int* tmp = in; in = out; out = tmp;
    }
    if (i < N) row_start[i] = boffs[blockIdx.x] + in[t] - v;
}

__global__ void set_val_kernel(int* __restrict__ p, int v) { p[0] = v; }

// ---------------------------------------------------------------------------
// Register-tiled node transform: 64 nodes/block, W staged in LDS, thread
// computes a 4-row x 6-col tile (24 accumulators -> ~1 FMA per issue slot
// instead of 1 FMA per ~2.5 with the old 1-output-per-thread loop).
// X tile stride is DIN+1 to kill row-stride bank conflicts.
// Epilogue: accs -> LDS (reusing X buffer), coalesced ft write, el/er dots.
// ---------------------------------------------------------------------------
template <int DIN>
__global__ void ft_elr_tiled_kernel(const void* __restrict__ X, int kind,
                                    const int* __restrict__ mode,
                                    const float* __restrict__ W,
                                    const float* __restrict__ al, const float* __restrict__ ar,
                                    float* __restrict__ ft, float* __restrict__ elr, int N) {
    __shared__ float ws[DIN * 96];
    __shared__ float xb[64 * 97];            // X tile (stride DIN+1), reused as fs (stride 97)
    const int t = threadIdx.x;
    const int base = blockIdx.x * 64;
    const int m = *mode;

    // stage W
    for (int i = t; i < DIN * 96; i += 256) ws[i] = W[i];
    // stage X (zero-pad rows past N)
    for (int i = t; i < 64 * DIN; i += 256) {
        int ln = i / DIN, d = i - ln * DIN;
        int node = base + ln;
        float v = 0.f;
        if (node < N) {
            size_t idx = (size_t)node * DIN + d;
            if (kind == 1)   v = ((const float*)X)[idx];
            else if (m == 0) v = b2f(((const bf16*)X)[idx]);
            else             v = ((const float*)X)[idx];
        }
        xb[ln * (DIN + 1) + d] = v;
    }
    __syncthreads();

    const int cx = t & 15;        // 16 col groups of 6
    const int ry = t >> 4;        // 16 row groups of 4
    const int c0 = cx * 6;
    const int r0 = ry * 4;

    float acc[4][6];
#pragma unroll
    for (int i = 0; i < 4; ++i)
#pragma unroll
        for (int j = 0; j < 6; ++j) acc[i][j] = 0.f;

#pragma unroll 4
    for (int d = 0; d < DIN; ++d) {
        float xv[4];
#pragma unroll
        for (int i = 0; i < 4; ++i) xv[i] = xb[(r0 + i) * (DIN + 1) + d];
        const float* wr = ws + d * 96 + c0;
        float wv[6];
#pragma unroll
        for (int j = 0; j < 6; ++j) wv[j] = wr[j];
#pragma unroll
        for (int i = 0; i < 4; ++i)
#pragma unroll
            for (int j = 0; j < 6; ++j) acc[i][j] += xv[i] * wv[j];
    }
    __syncthreads();   // xb reads done; safe to overwrite as fs

    // accs -> fs (stride 97)
#pragma unroll
    for (int i = 0; i < 4; ++i) {
        float* fr = xb + (r0 + i) * 97 + c0;
#pragma unroll
        for (int j = 0; j < 6; ++j) fr[j] = acc[i][j];
    }
    __syncthreads();

    // coalesced ft write
    for (int i = t; i < 64 * 96; i += 256) {
        int ln = i / 96, c = i - ln * 96;
        int node = base + ln;
        if (node < N) ft[(size_t)node * 96 + c] = xb[ln * 97 + c];
    }
    // el/er dots: 64 nodes x 6 (h x {l,r})
    for (int i = t; i < 384; i += 256) {
        int ln = i / 6, q = i - ln * 6;
        int h = q >> 1, isr = q & 1;
        int node = base + ln;
        if (node < N) {
            const float* av = (isr ? ar : al) + h * 32;
            const float* fr = xb + ln * 97 + h * 32;
            float acc2 = 0.f;
#pragma unroll
            for (int f = 0; f < 32; ++f) acc2 += fr[f] * av[f];
            elr[node * 6 + isr * 3 + h] = acc2;
        }
    }
}

// ---------------------------------------------------------------------------
// Fused scatter + both layers' edge-feature dots in ONE sequential sweep over
// efeats.  Pure streaming: no atomics (rank precomputed), no elr reads.
// Per edge: sequential 64B efeats row, ee1/ee2 dots, ONE random 32B write.
// ---------------------------------------------------------------------------
__global__ void scatter_edge_kernel(const void* __restrict__ ef, const int* __restrict__ mode,
                                    const float* __restrict__ wae1, const float* __restrict__ wae2,
                                    const int* __restrict__ src, const int* __restrict__ dst,
                                    const int* __restrict__ rank,
                                    const int* __restrict__ row_start,
                                    float4* __restrict__ S, int E) {
    __shared__ float w1[96];
    __shared__ float w2[96];
    int t = threadIdx.x;
    if (t < 96) { w1[t] = wae1[t]; w2[t] = wae2[t]; }
    __syncthreads();
    int e = blockIdx.x * blockDim.x + t;
    if (e >= E) return;
    int m = *mode;

    float x[32];
    if (m == 0) {
        const uint4* p = (const uint4*)((const uint16_t*)ef + (size_t)e * 32);
#pragma unroll
        for (int q = 0; q < 4; ++q) {
            uint4 u = p[q];
            x[q * 8 + 0] = bits2f(u.x << 16); x[q * 8 + 1] = bits2f(u.x & 0xffff0000u);
            x[q * 8 + 2] = bits2f(u.y << 16); x[q * 8 + 3] = bits2f(u.y & 0xffff0000u);
            x[q * 8 + 4] = bits2f(u.z << 16); x[q * 8 + 5] = bits2f(u.z & 0xffff0000u);
            x[q * 8 + 6] = bits2f(u.w << 16); x[q * 8 + 7] = bits2f(u.w & 0xffff0000u);
        }
    } else {
        const float4* p = (const float4*)((const float*)ef + (size_t)e * 32);
#pragma unroll
        for (int q = 0; q < 8; ++q) {
            float4 u = p[q];
            x[q * 4 + 0] = u.x; x[q * 4 + 1] = u.y; x[q * 4 + 2] = u.z; x[q * 4 + 3] = u.w;
        }
    }
    float a0 = 0.f, a1 = 0.f, a2 = 0.f;   // ee1
    float c0 = 0.f, c1 = 0.f, c2 = 0.f;   // ee2
#pragma unroll
    for (int d = 0; d < 32; ++d) {
        float xv = x[d];
        a0 += xv * w1[d * 3 + 0];
        a1 += xv * w1[d * 3 + 1];
        a2 += xv * w1[d * 3 + 2];
        c0 += xv * w2[d * 3 + 0];
        c1 += xv * w2[d * 3 + 1];
        c2 += xv * w2[d * 3 + 2];
    }
    int si = src[e], di = dst[e];
    int pos = row_start[di] + rank[e];
    S[2 * pos]     = make_float4(__int_as_float(si), a0, a1, a2);
    S[2 * pos + 1] = make_float4(c0, c1, c2, 0.f);
}

// ---------------------------------------------------------------------------
// Aggregation with fused edge softmax (both layers).
// ---------------------------------------------------------------------------
__global__ void aggregate_kernel(const float* __restrict__ ft, const float4* __restrict__ S,
                                 const int* __restrict__ row_start,
                                 const float* __restrict__ elr,
                                 const float* __restrict__ bias,
                                 int use_qa, int do_relu,
                                 float* __restrict__ R, int N) {
    int t = threadIdx.x;
    int node = blockIdx.x * 8 + (t >> 5);
    int lane = t & 31;
    if (node >= N) return;
    int beg = row_start[node], end = row_start[node + 1];
    float er0 = elr[node * 6 + 3], er1 = elr[node * 6 + 4], er2 = elr[node * 6 + 5];
    float a0 = 0.f, a1 = 0.f, a2 = 0.f, s0 = 0.f, s1 = 0.f, s2 = 0.f;
    int i = beg;
    for (; i + 4 <= end; i += 4) {
#pragma unroll
        for (int u = 0; u < 4; ++u) {
            float4 qa = S[2 * (i + u)];
            float4 qb = S[2 * (i + u) + 1];
            int sv = __float_as_int(qa.x);
            float ee0, ee1, ee2;
            if (use_qa) { ee0 = qa.y; ee1 = qa.z; ee2 = qa.w; }
            else        { ee0 = qb.x; ee1 = qb.y; ee2 = qb.z; }
            float2 el01 = *(const float2*)(elr + sv * 6);
            float  el2  = elr[sv * 6 + 2];
            float l0 = el01.x + er0 + ee0;
            float l1 = el01.y + er1 + ee1;
            float l2 = el2    + er2 + ee2;
            l0 = (l0 > 0.f) ? l0 : 0.2f * l0;
            l1 = (l1 > 0.f) ? l1 : 0.2f * l1;
            l2 = (l2 > 0.f) ? l2 : 0.2f * l2;
            float e0 = __expf(l0), e1 = __expf(l1), e2 = __expf(l2);
            const float* fr = ft + (size_t)sv * 96;
            a0 += fr[lane] * e0;
            a1 += fr[lane + 32] * e1;
            a2 += fr[lane + 64] * e2;
            s0 += e0; s1 += e1; s2 += e2;
        }
    }
    for (; i < end; ++i) {
        float4 qa = S[2 * i];
        float4 qb = S[2 * i + 1];
        int sv = __float_as_int(qa.x);
        float ee0, ee1, ee2;
        if (use_qa) { ee0 = qa.y; ee1 = qa.z; ee2 = qa.w; }
        else        { ee0 = qb.x; ee1 = qb.y; ee2 = qb.z; }
        float2 el01 = *(const float2*)(elr + sv * 6);
        float  el2  = elr[sv * 6 + 2];
        float l0 = el01.x + er0 + ee0;
        float l1 = el01.y + er1 + ee1;
        float l2 = el2    + er2 + ee2;
        l0 = (l0 > 0.f) ? l0 : 0.2f * l0;
        l1 = (l1 > 0.f) ? l1 : 0.2f * l1;
        l2 = (l2 > 0.f) ? l2 : 0.2f * l2;
        float e0 = __expf(l0), e1 = __expf(l1), e2 = __expf(l2);
        const float* fr = ft + (size_t)sv * 96;
        a0 += fr[lane] * e0;
        a1 += fr[lane + 32] * e1;
        a2 += fr[lane + 64] * e2;
        s0 += e0; s1 += e1; s2 += e2;
    }
    float r0, r1, r2;
    if (end > beg) { r0 = a0 / s0; r1 = a1 / s1; r2 = a2 / s2; }
    else           { r0 = r1 = r2 = 0.f; }
    r0 += bias[lane]; r1 += bias[lane + 32]; r2 += bias[lane + 64];
    if (do_relu) { r0 = fmaxf(r0, 0.f); r1 = fmaxf(r1, 0.f); r2 = fmaxf(r2, 0.f); }
    float* out = R + (size_t)node * 96;
    out[lane] = r0; out[lane + 32] = r1; out[lane + 64] = r2;
}

// Per node (8/block): u[n,c] = h@Wp[0:96,c] + bp[c]; v[n,c] = h@Wp[96:,c]
__global__ void uv_kernel(const float* __restrict__ h, const float* __restrict__ Wp,
                          const float* __restrict__ bp, float* __restrict__ uv, int N) {
    __shared__ float hs[8 * 96];
    int base = blockIdx.x * 8;
    int t = threadIdx.x;
    for (int i = t; i < 768; i += 256) {
        int ln = i / 96, c = i - ln * 96;
        int node = base + ln;
        hs[i] = (node < N) ? h[(size_t)node * 96 + c] : 0.f;
    }
    __syncthreads();
    if (t < 160) {
        int ln = t / 20, q = t - ln * 20;
        int half = q / 10, c = q - half * 10;
        int node = base + ln;
        if (node < N) {
            float acc = half ? 0.f : bp[c];
            const float* hr = hs + ln * 96;
            const float* wcol = Wp + half * 960 + c;
            for (int j = 0; j < 96; ++j) acc += hr[j] * wcol[j * 10];
            uv[node * 20 + q] = acc;
        }
    }
}

__global__ void score_kernel(const float* __restrict__ uv, const int* __restrict__ src,
                             const int* __restrict__ dst, const int* __restrict__ mode,
                             void* __restrict__ out, int E) {
    int e = blockIdx.x * blockDim.x + threadIdx.x;
    if (e >= E) return;
    int si = src[e], di = dst[e];
    const float* u = uv + (size_t)si * 20;
    const float* v = uv + (size_t)di * 20 + 10;
    float r[10];
#pragma unroll
    for (int c = 0; c < 10; ++c) r[c] = u[c] + v[c];
    if (*mode == 0) {
        bf16 o[10];
#pragma unroll
        for (int c = 0; c < 10; ++c) o[c] = __float2bfloat16(r[c]);
        uint32_t* po = (uint32_t*)((bf16*)out + (size_t)e * 10);
        const uint32_t* ps = (const uint32_t*)o;
#pragma unroll
        for (int q = 0; q < 5; ++q) po[q] = ps[q];
    } else {
        float2* po = (float2*)((float*)out + (size_t)e * 10);
#pragma unroll
        for (int q = 0; q < 5; ++q) po[q] = make_float2(r[2 * q], r[2 * q + 1]);
    }
}

extern "C" void kernel_launch(void* const* d_in, const int* in_sizes, int n_in,
                              void* d_out, int out_size, void* d_ws, size_t ws_size,
                              hipStream_t stream) {
    const void* nfeats = d_in[0];
    const void* efeats = d_in[1];
    const int* src = (const int*)d_in[2];
    const int* dst = (const int*)d_in[3];

    const int N = in_sizes[0] / 64;
    const int E = in_sizes[2];

    // ---- workspace (~138 MB) ----
    char* w = (char*)d_ws;
    auto alloc = [&](size_t bytes) {
        void* p = (void*)w;
        w += (bytes + 255) & ~(size_t)255;
        return p;
    };
    int*    flag      = (int*)alloc(256);
    float*  pbuf      = (float*)alloc((size_t)24202 * 4);
    float*  wae1      = (float*)alloc(96 * 4);
    float*  wae2      = (float*)alloc(96 * 4);
    float*  R         = (float*)alloc((size_t)N * 96 * 4);   // h (aggregate out)
    float*  F         = (float*)alloc((size_t)N * 96 * 4);   // ft per layer
    float4* S         = (float4*)alloc((size_t)E * 32);      // {src, ee1*3}{ee2*3, pad}
    float*  elr       = (float*)alloc((size_t)N * 6 * 4);
    int*    row_start = (int*)alloc((size_t)(N + 1) * 4);
    int*    cnt       = (int*)alloc((size_t)N * 4);
    int*    bsums     = (int*)alloc(512 * 4);
    int*    rank      = (int*)alloc((size_t)E * 4);
    float*  uv        = (float*)S;                            // S dead after layer 2

    const int ns[14] = {64*96, 32*96, 96, 96, 96, 96, 96*96, 32*96, 96, 96, 96, 96, 192*10, 10};
    ParamTable T;
    int off = 0;
    for (int k = 0; k < 14; ++k) { T.src[k] = d_in[4 + k]; T.off[k] = off; off += ns[k]; }
    T.off[14] = off;
    float* W1f  = pbuf + T.off[0];
    float* We1f = pbuf + T.off[1];
    float* al1f = pbuf + T.off[2];
    float* ar1f = pbuf + T.off[3];
    float* ae1f = pbuf + T.off[4];
    float* b1f  = pbuf + T.off[5];
    float* W2f  = pbuf + T.off[6];
    float* We2f = pbuf + T.off[7];
    float* al2f = pbuf + T.off[8];
    float* ar2f = pbuf + T.off[9];
    float* ae2f = pbuf + T.off[10];
    float* b2f_ = pbuf + T.off[11];
    float* Wpf  = pbuf + T.off[12];
    float* bpf  = pbuf + T.off[13];

    dim3 b256(256);
    int eblocks    = (E + 255) / 256;
    int nodeBlocks = (N + 7) / 8;
    int tileBlocks = (N + 63) / 64;
    int nb         = (N + 255) / 256;

    hipLaunchKernelGGL(detect_mode_kernel, dim3(1), dim3(64), 0, stream,
                       (const uint16_t*)nfeats, flag);
    hipLaunchKernelGGL(convert_params_kernel, dim3((off + 255) / 256), b256, 0, stream,
                       T, flag, pbuf);
    hipLaunchKernelGGL(fold_wae_kernel, dim3(1), dim3(128), 0, stream, We1f, ae1f, wae1);
    hipLaunchKernelGGL(fold_wae_kernel, dim3(1), dim3(128), 0, stream, We2f, ae2f, wae2);

    // ---- CSR offsets + per-edge rank ----
    hipMemsetAsync(cnt, 0, (size_t)N * 4, stream);
    hipLaunchKernelGGL(hist_rank_kernel, dim3(eblocks), b256, 0, stream, dst, cnt, rank, E);
    hipLaunchKernelGGL(block_sum_kernel, dim3(nb), b256, 0, stream, cnt, bsums, N);
    hipLaunchKernelGGL(scan_bsums_kernel, dim3(1), dim3(512), 0, stream, bsums, nb);
    hipLaunchKernelGGL(scan_expand_kernel, dim3(nb), b256, 0, stream, cnt, bsums, row_start, N);
    hipLaunchKernelGGL(set_val_kernel, dim3(1), dim3(1), 0, stream, row_start + N, E);

    // ---- fused scatter + both layers' edge-feature dots (ONE efeats sweep) ----
    hipLaunchKernelGGL(scatter_edge_kernel, dim3(eblocks), b256, 0, stream,
                       efeats, flag, wae1, wae2, src, dst, rank, row_start, S, E);

    // ---- layer 1 ----
    hipLaunchKernelGGL((ft_elr_tiled_kernel<64>), dim3(tileBlocks), b256, 0, stream,
                       nfeats, 0, flag, W1f, al1f, ar1f, F, elr, N);
    hipLaunchKernelGGL(aggregate_kernel, dim3(nodeBlocks), b256, 0, stream,
                       F, S, row_start, elr, b1f, 1, 1, R, N);

    // ---- layer 2 ----
    hipLaunchKernelGGL((ft_elr_tiled_kernel<96>), dim3(tileBlocks), b256, 0, stream,
                       (const void*)R, 1, flag, W2f, al2f, ar2f, F, elr, N);
    hipLaunchKernelGGL(aggregate_kernel, dim3(nodeBlocks), b256, 0, stream,
                       F, S, row_start, elr, b2f_, 0, 0, R, N);

    // ---- predictor ----
    hipLaunchKernelGGL(uv_kernel, dim3(nodeBlocks), b256, 0, stream, R, Wpf, bpf, uv, N);
    hipLaunchKernelGGL(score_kernel, dim3(eblocks), b256, 0, stream,
                       uv, src, dst, flag, d_out, E);
}